// Round 7
// baseline (295.472 us; speedup 1.0000x reference)
//
#include <hip/hip_runtime.h>
#include <stdint.h>

typedef float f32x4 __attribute__((ext_vector_type(4)));
typedef short s16x8 __attribute__((ext_vector_type(8)));
typedef short s16x4 __attribute__((ext_vector_type(4)));

static constexpr int NR = 16384;

__device__ __forceinline__ unsigned short f2bf(float f) {
    uint32_t u = __float_as_uint(f);
    u += 0x7FFFu + ((u >> 16) & 1u);   // round-to-nearest-even
    return (unsigned short)(u >> 16);
}

// ---------- prep: normalize mem rows, emit MFMA-fragment-packed bf16 ----------
// packed tile (ct,kb): 512 shorts at (ct*(C/32)+kb)*512;
// short lane*8+j = B[col=ct*16+(lane&15)][k=kb*32+(lane>>4)*8+j]
template<int C>
__device__ __forceinline__ void prep_body(const float* __restrict__ mp,
                                          short* __restrict__ nmp,
                                          int ct, short* stage) {
    const int tid = threadIdx.x;       // 256 threads
    const int row = tid >> 4;          // 0..15 (B column)
    const int c4  = tid & 15;
    constexpr int IT = C / 64;
    const f32x4* src = (const f32x4*)(mp + (size_t)(ct * 16 + row) * C);
    f32x4 vals[IT];
    float ss = 0.f;
#pragma unroll
    for (int i = 0; i < IT; ++i) {
        f32x4 v = src[c4 + 16 * i];
        vals[i] = v;
        ss += v.x * v.x + v.y * v.y + v.z * v.z + v.w * v.w;
    }
#pragma unroll
    for (int m = 1; m < 16; m <<= 1) ss += __shfl_xor(ss, m);
    const float inv = 1.f / fmaxf(sqrtf(ss), 1e-12f);
#pragma unroll
    for (int i = 0; i < IT; ++i) {
        f32x4 v = vals[i];
        s16x4 o;
        o[0] = (short)f2bf(v.x * inv);
        o[1] = (short)f2bf(v.y * inv);
        o[2] = (short)f2bf(v.z * inv);
        o[3] = (short)f2bf(v.w * inv);
        *(s16x4*)&stage[row * C + (c4 + 16 * i) * 4] = o;
    }
    __syncthreads();
    const int lane = tid & 63;
    const int wv = tid >> 6;
    constexpr int NKB = C / 32;
#pragma unroll
    for (int j = 0; j < NKB / 4; ++j) {
        const int kb = j * 4 + wv;
        const s16x8 v = *(const s16x8*)&stage[(lane & 15) * C + kb * 32 + (lane >> 4) * 8];
        *(s16x8*)&nmp[((size_t)ct * NKB + kb) * 512 + lane * 8] = v;
    }
}

__global__ __launch_bounds__(256) void prep_all(const float* m0, short* n0,
                                                const float* m1, short* n1,
                                                const float* m2, short* n2) {
    __shared__ short stage[16 * 1024];
    const int bid = blockIdx.x;
    if (bid < 64) prep_body<256>(m0, n0, bid, stage);
    else if (bid < 128) prep_body<512>(m1, n1, bid - 64, stage);
    else prep_body<1024>(m2, n2, bid - 128, stage);
}

// ---------- copy kernel: pure streaming ----------
// reads f once; writes f-copy; invn -> ws; packed bf16 A fragments stashed in
// the mf half of out_cat (row r's slot = floats [r*2C, r*2C+C); fragment
// (t16,kb) -> slot_row t16*16+(kb&15), short offset (kb>>4)*512).
template<int C>
__device__ __forceinline__ void copy_body(const float* __restrict__ feat,
                                          float* __restrict__ out_cat,
                                          float* __restrict__ inv_arr,
                                          int tt, short* S) {
    const int tid = threadIdx.x;        // 256
    const int row = tid >> 4;           // 0..15
    const int c4  = tid & 15;
    constexpr int IT = C / 64;
    const f32x4* src = (const f32x4*)(feat + (size_t)(tt * 16 + row) * C);
    f32x4* dstf = (f32x4*)(out_cat + (size_t)(tt * 16 + row) * (2 * C) + C);
    float ss = 0.f;
#pragma unroll
    for (int i = 0; i < IT; ++i) {
        const int idx = c4 + 16 * i;
        f32x4 v = __builtin_nontemporal_load(&src[idx]);
        __builtin_nontemporal_store(v, &dstf[idx]);
        ss += v.x * v.x + v.y * v.y + v.z * v.z + v.w * v.w;
        s16x4 o;
        o[0] = (short)f2bf(v.x);
        o[1] = (short)f2bf(v.y);
        o[2] = (short)f2bf(v.z);
        o[3] = (short)f2bf(v.w);
        // 16B-granule XOR swizzle (granule idx>>1), matches fragment reads
        *(s16x4*)&S[row * C + (((idx >> 1) ^ (row & 7)) * 8) + (idx & 1) * 4] = o;
    }
#pragma unroll
    for (int m = 1; m < 16; m <<= 1) ss += __shfl_xor(ss, m);
    if (c4 == 0) inv_arr[tt * 16 + row] = 1.f / fmaxf(sqrtf(ss), 1e-12f);
    __syncthreads();
    // emit packed A fragments (coalesced 1KB per fragment)
    const int l = tid & 63;
    const int w = tid >> 6;
    short* pa = (short*)out_cat;
    constexpr int NKB = C / 32;
#pragma unroll
    for (int j = 0; j < NKB / 4; ++j) {
        const int kb = 4 * j + w;
        const s16x8 v = *(const s16x8*)&S[(l & 15) * C + ((((kb * 4) + (l >> 4)) ^ (l & 7)) * 8)];
        short* dst = pa + ((size_t)(tt * 16 + (kb & 15))) * 4 * C + (kb >> 4) * 512 + l * 8;
        *(s16x8*)dst = v;      // normal store: want it resident in L3 for GEMM
    }
}

__global__ __launch_bounds__(256) void copy_all(const float* f0, float* o0,
                                                const float* f1, float* o1,
                                                const float* f2, float* o2,
                                                float* invA) {
    __shared__ short S[16 * 1024];
    const int bid = blockIdx.x;
    if (bid < 1024) copy_body<1024>(f2, o2, invA + 2 * NR, bid, S);
    else if (bid < 2048) copy_body<512>(f1, o1, invA + NR, bid - 1024, S);
    else copy_body<256>(f0, o0, invA, bid - 2048, S);
}

// ---------- GEMM kernel: no LDS / no barriers in the K-loop ----------
template<int C>
__device__ __forceinline__ void gemm_body(const float* __restrict__ memv,
                                          const short* __restrict__ nm,
                                          const float* __restrict__ inv_arr,
                                          float* __restrict__ out_cat,
                                          float* __restrict__ out_w,
                                          int tile, float* Wt, float (*red)[32],
                                          float* invL, int* rowflag, int* anyflag) {
    constexpr int NKB = C / 32;
    const int tid = threadIdx.x;
    const int wave = tid >> 6;
    const int lane = tid & 63;
    const int g = lane >> 4;
    const int ml = lane & 15;
    const int row0 = tile * 32;

    if (tid == 0) *anyflag = 0;
    if (tid < 32) invL[tid] = inv_arr[row0 + tid];

    f32x4 acc[2][8];
#pragma unroll
    for (int rt = 0; rt < 2; ++rt)
#pragma unroll
        for (int t = 0; t < 8; ++t)
            acc[rt][t] = (f32x4){0.f, 0.f, 0.f, 0.f};

    const short* pa = (const short*)out_cat;
    const short* pa0 = pa + (size_t)(tile * 2 + 0) * 16 * 4 * C + lane * 8;
    const short* pa1 = pa + (size_t)(tile * 2 + 1) * 16 * 4 * C + lane * 8;
    const short* nbb = nm + (size_t)(wave * 8) * NKB * 512 + lane * 8;

#pragma unroll 2
    for (int kb = 0; kb < NKB; ++kb) {
        const size_t aoff = (size_t)(kb & 15) * 4 * C + (kb >> 4) * 512;
        const s16x8 a0 = __builtin_nontemporal_load((const s16x8*)(pa0 + aoff));
        const s16x8 a1 = __builtin_nontemporal_load((const s16x8*)(pa1 + aoff));
        const short* nb = nbb + (size_t)kb * 512;
#pragma unroll
        for (int t = 0; t < 8; ++t) {
            const s16x8 b = *(const s16x8*)(nb + (size_t)t * NKB * 512);
            acc[0][t] = __builtin_amdgcn_mfma_f32_16x16x32_bf16(a0, b, acc[0][t], 0, 0, 0);
            acc[1][t] = __builtin_amdgcn_mfma_f32_16x16x32_bf16(a1, b, acc[1][t], 0, 0, 0);
        }
    }
    __syncthreads();                      // S1: invL visible

    // C/D layout: col = ml, row = 16*rt + 4*g + i
    float Tt[2][4], IL[2][4];

    // ---- exp (no max-sub: |S| <= 1) + row sum ----
#pragma unroll
    for (int rt = 0; rt < 2; ++rt)
#pragma unroll
        for (int i = 0; i < 4; ++i) {
            const float inv = invL[rt * 16 + g * 4 + i];
            float s = 0.f;
#pragma unroll
            for (int t = 0; t < 8; ++t) {
                const float e = __expf(acc[rt][t][i] * inv);
                acc[rt][t][i] = e;
                s += e;
            }
#pragma unroll
            for (int msk = 1; msk < 16; msk <<= 1) s += __shfl_xor(s, msk);
            if (ml == 0) red[wave][rt * 16 + g * 4 + i] = s;
        }
    __syncthreads();                      // S2: red ready
#pragma unroll
    for (int rt = 0; rt < 2; ++rt)
#pragma unroll
        for (int i = 0; i < 4; ++i) {
            const int row = rt * 16 + g * 4 + i;
            float s = red[0][row];
#pragma unroll
            for (int ww = 1; ww < 8; ++ww) s += red[ww][row];
            Tt[rt][i] = s;
        }

    // ---- softmax weight, hard-shrink, row L1 (disjoint red half) ----
#pragma unroll
    for (int rt = 0; rt < 2; ++rt)
#pragma unroll
        for (int i = 0; i < 4; ++i) {
            const float tinv = 1.f / Tt[rt][i];
            float l1 = 0.f;
#pragma unroll
            for (int t = 0; t < 8; ++t) {
                const float w = acc[rt][t][i] * tinv;
                const float d = w - 0.0025f;
                const float v = (d > 0.f) ? (d * w / (d + 1e-12f)) : 0.f;
                acc[rt][t][i] = v;
                l1 += v;
            }
#pragma unroll
            for (int msk = 1; msk < 16; msk <<= 1) l1 += __shfl_xor(l1, msk);
            if (ml == 0) red[8 + wave][rt * 16 + g * 4 + i] = l1;
        }
    __syncthreads();                      // S3
#pragma unroll
    for (int rt = 0; rt < 2; ++rt)
#pragma unroll
        for (int i = 0; i < 4; ++i) {
            const int row = rt * 16 + g * 4 + i;
            float l1 = red[8][row];
#pragma unroll
            for (int ww = 1; ww < 8; ++ww) l1 += red[8 + ww][row];
            IL[rt][i] = 1.f / fmaxf(l1, 1e-12f);
            if (wave == 0 && ml == 0) {
                rowflag[row] = (l1 > 0.f) ? 1 : 0;
                if (l1 > 0.f) *anyflag = 1;
            }
        }

    // ---- W store via per-wave LDS transpose -> contiguous 512B runs ----
    float* wst = Wt + wave * 528;         // 4 rows x 132 (padded)
    const int r4 = lane >> 4;
    const int c8 = (lane & 15) * 8;
#pragma unroll
    for (int rt = 0; rt < 2; ++rt)
#pragma unroll
        for (int i = 0; i < 4; ++i) {
#pragma unroll
            for (int t = 0; t < 8; ++t)
                wst[g * 132 + t * 16 + ml] = acc[rt][t][i] * IL[rt][i];
            // same-wave LDS RAW: compiler inserts lgkmcnt wait
            const f32x4 o0 = *(const f32x4*)&wst[r4 * 132 + c8];
            const f32x4 o1 = *(const f32x4*)&wst[r4 * 132 + c8 + 4];
            float* orow = out_w + (size_t)(row0 + rt * 16 + r4 * 4 + i) * 1024 + wave * 128;
            __builtin_nontemporal_store(o0, (f32x4*)&orow[c8]);
            __builtin_nontemporal_store(o1, (f32x4*)&orow[c8 + 4]);
        }

    // ---- zero the mf half (also erases the packed-A stash) ----
    const int prow = tid >> 4;
    const int pc4 = tid & 15;
    f32x4* dstz = (f32x4*)(out_cat + (size_t)(row0 + prow) * (2 * C));
    const f32x4 z4 = {0.f, 0.f, 0.f, 0.f};
#pragma unroll
    for (int x = 0; x < C / 64; ++x)
        __builtin_nontemporal_store(z4, &dstz[pc4 + 16 * x]);
    __syncthreads();                      // S5: zeros+W drained before fixup

    // ---- mf fixup: only rows surviving the shrink ----
    if (*anyflag != 0) {
        constexpr int CC = C / 64;
#pragma unroll
        for (int rr = 0; rr < 4; ++rr) {
            const int row = wave * 4 + rr;
            if (!rowflag[row]) continue;
            float* dst = out_cat + (size_t)(row0 + row) * (2 * C);
            float mfacc[CC];
#pragma unroll
            for (int cc = 0; cc < CC; ++cc) mfacc[cc] = 0.f;
            const float* wrow = out_w + (size_t)(row0 + row) * 1024;
            for (int jb = 0; jb < 1024; jb += 64) {
                const float wv = wrow[jb + lane];
                unsigned long long msk = __ballot(wv != 0.f);
                while (msk) {
                    const int j = __builtin_ctzll(msk);
                    msk &= msk - 1;
                    const float val = __shfl(wv, j);
                    const float* mrow = memv + (size_t)(jb + j) * C;
#pragma unroll
                    for (int cc = 0; cc < CC; ++cc)
                        mfacc[cc] += val * mrow[cc * 64 + lane];
                }
            }
#pragma unroll
            for (int cc = 0; cc < CC; ++cc) dst[cc * 64 + lane] = mfacc[cc];
        }
    }
}

__global__ __launch_bounds__(512, 4) void gemm_all(
        const float* m0, const short* n0, float* o0, float* w0,
        const float* m1, const short* n1, float* o1, float* w1,
        const float* m2, const short* n2, float* o2, float* w2,
        const float* invA) {
    __shared__ float Wt[8 * 528];
    __shared__ float red[16][32];
    __shared__ float invL[32];
    __shared__ int rowflag[32];
    __shared__ int anyflag;

    const int bid = blockIdx.x;
    if (bid < 512)
        gemm_body<1024>(m2, n2, invA + 2 * NR, o2, w2, bid, Wt, red, invL, rowflag, &anyflag);
    else if (bid < 1024)
        gemm_body<512>(m1, n1, invA + NR, o1, w1, bid - 512, Wt, red, invL, rowflag, &anyflag);
    else
        gemm_body<256>(m0, n0, invA, o0, w0, bid - 1024, Wt, red, invL, rowflag, &anyflag);
}

extern "C" void kernel_launch(void* const* d_in, const int* in_sizes, int n_in,
                              void* d_out, int out_size, void* d_ws, size_t ws_size,
                              hipStream_t stream) {
    const float* feat[3] = {nullptr, nullptr, nullptr};
    const float* memp[3] = {nullptr, nullptr, nullptr};
    for (int i = 0; i < n_in && i < 6; ++i) {
        const int s = in_sizes[i];
        const float* p = (const float*)d_in[i];
        if (s == 16384 * 256) feat[0] = p;
        else if (s == 16384 * 512) feat[1] = p;
        else if (s == 16384 * 1024) feat[2] = p;
        else if (s == 1024 * 256) memp[0] = p;
        else if (s == 1024 * 512) memp[1] = p;
        else if (s == 1024 * 1024) memp[2] = p;
    }
    float* out = (float*)d_out;
    short* nm0 = (short*)d_ws;
    short* nm1 = nm0 + 1024 * 256;
    short* nm2 = nm1 + 1024 * 512;
    float* invA = (float*)(nm2 + 1024 * 1024);   // 3 x 16384 floats

    // output layout (floats): out0 | out1 | out2 | w0 | w1 | w2
    const size_t O0 = 0;
    const size_t O1 = (size_t)16384 * 512;
    const size_t O2 = O1 + (size_t)16384 * 1024;
    const size_t W0 = O2 + (size_t)16384 * 2048;
    const size_t W1 = W0 + (size_t)16384 * 1024;
    const size_t W2 = W1 + (size_t)16384 * 1024;

    prep_all<<<192, 256, 0, stream>>>(memp[0], nm0, memp[1], nm1, memp[2], nm2);

    copy_all<<<3072, 256, 0, stream>>>(feat[0], out + O0,
                                       feat[1], out + O1,
                                       feat[2], out + O2, invA);

    gemm_all<<<1536, 512, 0, stream>>>(
        memp[0], nm0, out + O0, out + W0,
        memp[1], nm1, out + O1, out + W1,
        memp[2], nm2, out + O2, out + W2, invA);
}